// Round 1
// baseline (4599.120 us; speedup 1.0000x reference)
//
#include <hip/hip_runtime.h>
#include <math.h>

#define NN   100000
#define E1N  3200000
#define C1N  25000
#define E2N  800000
#define C2N  6250
#define BN   64

// order-preserving float<->uint encoding (monotonic: float order == unsigned order).
// encoded(-inf) = 0x007FFFFF > 0, so a zero-initialized buffer acts as "below -inf".
__device__ __forceinline__ unsigned f2ord(float f){
  unsigned u = __float_as_uint(f);
  return (u & 0x80000000u) ? ~u : (u | 0x80000000u);
}
__device__ __forceinline__ float ord2f(unsigned u){
  return (u & 0x80000000u) ? __uint_as_float(u & 0x7fffffffu) : __uint_as_float(~u);
}

// h = x @ W1 (N x 3 -> N x 16); ad = h . att[:16]; as = h . att[16:]
__global__ void node1_k(const float* __restrict__ x, const float* __restrict__ W1,
                        const float* __restrict__ att1,
                        float* __restrict__ h, float* __restrict__ ad, float* __restrict__ as_){
  int n = blockIdx.x * blockDim.x + threadIdx.x;
  if (n >= NN) return;
  float x0 = x[n*3+0], x1 = x[n*3+1], x2 = x[n*3+2];
  float a = 0.f, b = 0.f;
  #pragma unroll
  for (int j = 0; j < 16; ++j){
    float v = x0*W1[j] + x1*W1[16+j] + x2*W1[32+j];
    h[(size_t)n*16 + j] = v;
    a += v * att1[j];
    b += v * att1[16+j];
  }
  ad[n] = a; as_[n] = b;
}

// pass 1: per-dst max of leaky_relu(ad[dst] + as[src])
__global__ void edge_max_k(const int* __restrict__ src, const int* __restrict__ dst,
                           const float* __restrict__ ad, const float* __restrict__ as_,
                           unsigned* __restrict__ m, int E){
  int e = blockIdx.x * blockDim.x + threadIdx.x;
  if (e >= E) return;
  int s = src[e], d = dst[e];
  float l = ad[d] + as_[s];
  l = l > 0.f ? l : 0.2f * l;
  atomicMax(&m[d], f2ord(l));
}

// pass 2 (fused): ex = exp(l - m[dst]); ssum[dst] += ex; agg[dst,:] += ex*w*h[src,:]
template<int D>
__global__ void edge_agg_k(const int* __restrict__ src, const int* __restrict__ dst,
                           const float* __restrict__ w,
                           const float* __restrict__ ad, const float* __restrict__ as_,
                           const unsigned* __restrict__ m, const float* __restrict__ h,
                           float* __restrict__ ssum, float* __restrict__ agg, int E){
  int e = blockIdx.x * blockDim.x + threadIdx.x;
  if (e >= E) return;
  int s = src[e], d = dst[e];
  float l = ad[d] + as_[s];
  l = l > 0.f ? l : 0.2f * l;
  float ex = expf(l - ord2f(m[d]));
  atomicAdd(&ssum[d], ex);
  float c = ex * w[e];
  const float* hs = h + (size_t)s * D;
  float* ag = agg + (size_t)d * D;
  #pragma unroll
  for (int j = 0; j < D; ++j) atomicAdd(&ag[j], c * hs[j]);
}

// out = relu(agg/ssum + bias); pooled[cluster] = max(pooled[cluster], out)
// relu output >= 0, so raw float bits compare correctly as unsigned; init 0 == 0.0f
// matches the reference's empty-cluster -> 0 guard.
template<int D>
__global__ void finish_pool_k(const float* __restrict__ agg, const float* __restrict__ ssum,
                              const float* __restrict__ bias, const int* __restrict__ cl,
                              unsigned* __restrict__ pooled, int n){
  int i = blockIdx.x * blockDim.x + threadIdx.x;
  if (i >= n) return;
  int c = cl[i];
  float sv = ssum[i];
  float inv = sv > 0.f ? 1.f / sv : 0.f;   // no-edge node: out = 0 + bias
  #pragma unroll
  for (int j = 0; j < D; ++j){
    float v = agg[(size_t)i*D + j] * inv + bias[j];
    v = v > 0.f ? v : 0.f;
    atomicMax(&pooled[(size_t)c*D + j], __float_as_uint(v));
  }
}

// h2 = hp @ W2 (C1 x 16 -> C1 x 32); ad2/as2 attention halves
__global__ void node2_k(const float* __restrict__ hp, const float* __restrict__ W2,
                        const float* __restrict__ att2,
                        float* __restrict__ h2, float* __restrict__ ad2, float* __restrict__ as2){
  int n = blockIdx.x * blockDim.x + threadIdx.x;
  if (n >= C1N) return;
  float hin[16];
  #pragma unroll
  for (int f = 0; f < 16; ++f) hin[f] = hp[(size_t)n*16 + f];
  float a = 0.f, b = 0.f;
  #pragma unroll
  for (int j = 0; j < 32; ++j){
    float v = 0.f;
    #pragma unroll
    for (int f = 0; f < 16; ++f) v += hin[f] * W2[f*32 + j];
    h2[(size_t)n*32 + j] = v;
    a += v * att2[j];
    b += v * att2[32 + j];
  }
  ad2[n] = a; as2[n] = b;
}

// scatter-mean numerators/denominators over batch
__global__ void readout_k(const float* __restrict__ hm, const int* __restrict__ batch,
                          float* __restrict__ gsum, float* __restrict__ gcnt){
  int c = blockIdx.x * blockDim.x + threadIdx.x;
  if (c >= C2N) return;
  int b = batch[c];
  atomicAdd(&gcnt[b], 1.f);
  #pragma unroll
  for (int j = 0; j < 32; ++j) atomicAdd(&gsum[(size_t)b*32 + j], hm[(size_t)c*32 + j]);
}

// per-graph MLP head: out = relu(g@Wfc1 + bfc1) @ Wfc2 + bfc2
__global__ void head_k(const float* __restrict__ gsum, const float* __restrict__ gcnt,
                       const float* __restrict__ Wfc1, const float* __restrict__ bfc1,
                       const float* __restrict__ Wfc2, const float* __restrict__ bfc2,
                       float* __restrict__ out){
  int b = threadIdx.x;
  if (b >= BN) return;
  float cnt = gcnt[b]; if (cnt < 1.f) cnt = 1.f;
  float g[32];
  #pragma unroll
  for (int j = 0; j < 32; ++j) g[j] = gsum[(size_t)b*32 + j] / cnt;
  float acc = 0.f;
  for (int k = 0; k < 64; ++k){
    float t = bfc1[k];
    #pragma unroll
    for (int j = 0; j < 32; ++j) t += g[j] * Wfc1[j*64 + k];
    t = t > 0.f ? t : 0.f;
    acc += t * Wfc2[k];
  }
  out[b] = acc + bfc2[0];
}

extern "C" void kernel_launch(void* const* d_in, const int* in_sizes, int n_in,
                              void* d_out, int out_size, void* d_ws, size_t ws_size,
                              hipStream_t stream) {
  const float* x        = (const float*)d_in[0];
  const int*   ei       = (const int*)  d_in[1];   // [2, E1]: src = ei, dst = ei+E1
  const float* ea       = (const float*)d_in[2];
  const int*   cluster1 = (const int*)  d_in[3];
  const int*   ei2      = (const int*)  d_in[4];   // [2, E2]
  const float* ea2      = (const float*)d_in[5];
  const int*   cluster2 = (const int*)  d_in[6];
  const int*   batch    = (const int*)  d_in[7];
  const float* W1   = (const float*)d_in[8];
  const float* att1 = (const float*)d_in[9];
  const float* b1   = (const float*)d_in[10];
  const float* W2   = (const float*)d_in[11];
  const float* att2 = (const float*)d_in[12];
  const float* b2   = (const float*)d_in[13];
  const float* Wfc1 = (const float*)d_in[14];
  const float* bfc1 = (const float*)d_in[15];
  const float* Wfc2 = (const float*)d_in[16];
  const float* bfc2 = (const float*)d_in[17];

  float* ws = (float*)d_ws;
  // ---- zero-initialized block (one memset) ----
  float* m1   = ws;                         // NN      (ord-encoded uint)
  float* s1   = m1   + NN;                  // NN
  float* agg1 = s1   + NN;                  // NN*16
  float* hp   = agg1 + (size_t)NN*16;       // C1N*16  (float bits via atomicMax)
  float* m2   = hp   + (size_t)C1N*16;      // C1N
  float* s2   = m2   + C1N;                 // C1N
  float* agg2 = s2   + C1N;                 // C1N*32
  float* hm   = agg2 + (size_t)C1N*32;      // C2N*32
  float* gsum = hm   + (size_t)C2N*32;      // BN*32
  float* gcnt = gsum + (size_t)BN*32;       // BN
  float* zend = gcnt + BN;
  size_t zbytes = (size_t)((char*)zend - (char*)ws);
  // ---- write-before-read block (no init needed) ----
  float* h1  = zend;                        // NN*16
  float* ad1 = h1  + (size_t)NN*16;         // NN
  float* as1 = ad1 + NN;                    // NN
  float* h2  = as1 + NN;                    // C1N*32
  float* ad2 = h2  + (size_t)C1N*32;        // C1N
  float* as2 = ad2 + C1N;                   // C1N

  hipMemsetAsync(ws, 0, zbytes, stream);

  // conv1
  node1_k<<<(NN + 255)/256, 256, 0, stream>>>(x, W1, att1, h1, ad1, as1);
  edge_max_k<<<(E1N + 255)/256, 256, 0, stream>>>(ei, ei + E1N, ad1, as1, (unsigned*)m1, E1N);
  edge_agg_k<16><<<(E1N + 255)/256, 256, 0, stream>>>(ei, ei + E1N, ea, ad1, as1,
                                                      (const unsigned*)m1, h1, s1, agg1, E1N);
  finish_pool_k<16><<<(NN + 255)/256, 256, 0, stream>>>(agg1, s1, b1, cluster1,
                                                        (unsigned*)hp, NN);
  // conv2
  node2_k<<<(C1N + 255)/256, 256, 0, stream>>>(hp, W2, att2, h2, ad2, as2);
  edge_max_k<<<(E2N + 255)/256, 256, 0, stream>>>(ei2, ei2 + E2N, ad2, as2, (unsigned*)m2, E2N);
  edge_agg_k<32><<<(E2N + 255)/256, 256, 0, stream>>>(ei2, ei2 + E2N, ea2, ad2, as2,
                                                      (const unsigned*)m2, h2, s2, agg2, E2N);
  finish_pool_k<32><<<(C1N + 255)/256, 256, 0, stream>>>(agg2, s2, b2, cluster2,
                                                         (unsigned*)hm, C1N);
  // readout + head
  readout_k<<<(C2N + 255)/256, 256, 0, stream>>>(hm, batch, gsum, gcnt);
  head_k<<<1, 64, 0, stream>>>(gsum, gcnt, Wfc1, bfc1, Wfc2, bfc2, (float*)d_out);
}

// Round 2
// 857.291 us; speedup vs baseline: 5.3647x; 5.3647x over previous
//
#include <hip/hip_runtime.h>
#include <math.h>

#define NN   100000
#define E1N  3200000
#define C1N  25000
#define E2N  800000
#define C2N  6250
#define BN   64

// ---------------- node feature transforms ----------------

// h = x @ W1 (N x 3 -> N x 16); ad = h . att[:16]; as = h . att[16:]
__global__ void node1_k(const float* __restrict__ x, const float* __restrict__ W1,
                        const float* __restrict__ att1,
                        float* __restrict__ h, float* __restrict__ ad, float* __restrict__ as_){
  int n = blockIdx.x * blockDim.x + threadIdx.x;
  if (n >= NN) return;
  float x0 = x[n*3+0], x1 = x[n*3+1], x2 = x[n*3+2];
  float a = 0.f, b = 0.f;
  #pragma unroll
  for (int j = 0; j < 16; ++j){
    float v = x0*W1[j] + x1*W1[16+j] + x2*W1[32+j];
    h[(size_t)n*16 + j] = v;
    a += v * att1[j];
    b += v * att1[16+j];
  }
  ad[n] = a; as_[n] = b;
}

// h2 = hp @ W2 (C1 x 16 -> C1 x 32); ad2/as2 attention halves
__global__ void node2_k(const float* __restrict__ hp, const float* __restrict__ W2,
                        const float* __restrict__ att2,
                        float* __restrict__ h2, float* __restrict__ ad2, float* __restrict__ as2){
  int n = blockIdx.x * blockDim.x + threadIdx.x;
  if (n >= C1N) return;
  float hin[16];
  #pragma unroll
  for (int f = 0; f < 16; ++f) hin[f] = hp[(size_t)n*16 + f];
  float a = 0.f, b = 0.f;
  #pragma unroll
  for (int j = 0; j < 32; ++j){
    float v = 0.f;
    #pragma unroll
    for (int f = 0; f < 16; ++f) v += hin[f] * W2[f*32 + j];
    h2[(size_t)n*32 + j] = v;
    a += v * att2[j];
    b += v * att2[32 + j];
  }
  ad2[n] = a; as2[n] = b;
}

// ---------------- CSR build: degree -> scan -> scatter ----------------

__global__ void deg_k(const int* __restrict__ dst, int* __restrict__ deg, int E){
  int e = blockIdx.x * blockDim.x + threadIdx.x;
  if (e >= E) return;
  atomicAdd(&deg[dst[e]], 1);
}

#define SCAN_T 256
#define SCAN_E 4   // elements per thread -> 1024 per block

// inclusive scan within each 1024-block; block totals to bsum
__global__ void scan_block_k(const int* __restrict__ in, int* __restrict__ out,
                             int* __restrict__ bsum, int n){
  __shared__ int lds[SCAN_T];
  int t = threadIdx.x;
  int base = blockIdx.x * (SCAN_T*SCAN_E);
  int vals[SCAN_E];
  int acc = 0;
  #pragma unroll
  for (int k = 0; k < SCAN_E; ++k){
    int i = base + t*SCAN_E + k;
    vals[k] = (i < n) ? in[i] : 0;
    acc += vals[k];
  }
  lds[t] = acc;
  __syncthreads();
  #pragma unroll
  for (int off = 1; off < SCAN_T; off <<= 1){
    int v = (t >= off) ? lds[t-off] : 0;
    __syncthreads();
    lds[t] += v;
    __syncthreads();
  }
  int run = (t > 0) ? lds[t-1] : 0;
  #pragma unroll
  for (int k = 0; k < SCAN_E; ++k){
    int i = base + t*SCAN_E + k;
    run += vals[k];
    if (i < n) out[i] = run;
  }
  if (t == SCAN_T-1) bsum[blockIdx.x] = lds[SCAN_T-1];
}

// serial inclusive scan of block sums (nb <= 256)
__global__ void scan_top_k(int* __restrict__ bsum, int nb){
  if (threadIdx.x == 0){
    int run = 0;
    for (int b = 0; b < nb; ++b){ run += bsum[b]; bsum[b] = run; }
  }
}

__global__ void scan_add_k(int* __restrict__ out, const int* __restrict__ bsum, int n){
  int b = blockIdx.x;
  if (b == 0) return;
  int add = bsum[b-1];
  int i0 = b*(SCAN_T*SCAN_E) + threadIdx.x;
  #pragma unroll
  for (int k = 0; k < SCAN_E; ++k){
    int i = i0 + k*SCAN_T;
    if (i < n) out[i] += add;
  }
}

// scatter edges into CSR slots: payload = src id + edge weight
__global__ void scatter_k(const int* __restrict__ src, const int* __restrict__ dst,
                          const float* __restrict__ w, const int* __restrict__ row,
                          int* __restrict__ cur, int* __restrict__ csrc,
                          float* __restrict__ cwv, int E){
  int e = blockIdx.x * blockDim.x + threadIdx.x;
  if (e >= E) return;
  int d = dst[e];
  int p = row[d] + atomicAdd(&cur[d], 1);
  csrc[p] = src[e];
  cwv[p]  = w[e];
}

// ---------------- fused per-dst softmax-aggregate + relu + cluster max-pool ----------------
// GRP lanes cooperate on one dst. Two passes over its CSR range:
//   pass 1: m = max leaky_relu(ad[dst] + as[src])
//   pass 2: s += ex, acc += ex*w*h[src]   (ex = exp(l - m))
// epilogue: out = relu(acc/s + bias), atomicMax into pooled[cluster].
template<int D, int GRP>
__global__ void agg_pool_k(const int* __restrict__ row,
                           const int* __restrict__ csrc, const float* __restrict__ cwv,
                           const float* __restrict__ ad, const float* __restrict__ as_,
                           const float* __restrict__ h, const float* __restrict__ bias,
                           const int* __restrict__ cl, unsigned* __restrict__ pooled, int n){
  int gid  = (blockIdx.x * blockDim.x + threadIdx.x) / GRP;
  int lane = threadIdx.x & (GRP-1);
  if (gid >= n) return;
  int beg = row[gid], end = row[gid+1];
  float adg = ad[gid];

  float m = -3.0e38f;
  for (int p = beg + lane; p < end; p += GRP){
    float l = adg + as_[csrc[p]];
    l = l > 0.f ? l : 0.2f*l;
    m = fmaxf(m, l);
  }
  #pragma unroll
  for (int off = GRP>>1; off; off >>= 1) m = fmaxf(m, __shfl_xor(m, off));

  float s = 0.f;
  float4 acc[D/4];
  #pragma unroll
  for (int j = 0; j < D/4; ++j) acc[j] = make_float4(0.f,0.f,0.f,0.f);

  for (int p = beg + lane; p < end; p += GRP){
    int sv = csrc[p];
    float l = adg + as_[sv];
    l = l > 0.f ? l : 0.2f*l;
    float ex = __expf(l - m);
    s += ex;
    float c = ex * cwv[p];
    const float4* hs = (const float4*)(h + (size_t)sv*D);
    #pragma unroll
    for (int j = 0; j < D/4; ++j){
      float4 hv = hs[j];
      acc[j].x += c*hv.x; acc[j].y += c*hv.y; acc[j].z += c*hv.z; acc[j].w += c*hv.w;
    }
  }
  #pragma unroll
  for (int off = GRP>>1; off; off >>= 1){
    s += __shfl_xor(s, off);
    #pragma unroll
    for (int j = 0; j < D/4; ++j){
      acc[j].x += __shfl_xor(acc[j].x, off);
      acc[j].y += __shfl_xor(acc[j].y, off);
      acc[j].z += __shfl_xor(acc[j].z, off);
      acc[j].w += __shfl_xor(acc[j].w, off);
    }
  }
  float inv = s > 0.f ? 1.f/s : 0.f;   // no-edge node: out = bias
  int c = cl[gid];
  if (lane == 0){
    #pragma unroll
    for (int j = 0; j < D/4; ++j){
      float4 a4 = acc[j];
      float v0 = a4.x*inv + bias[j*4+0]; v0 = v0 > 0.f ? v0 : 0.f;
      float v1 = a4.y*inv + bias[j*4+1]; v1 = v1 > 0.f ? v1 : 0.f;
      float v2 = a4.z*inv + bias[j*4+2]; v2 = v2 > 0.f ? v2 : 0.f;
      float v3 = a4.w*inv + bias[j*4+3]; v3 = v3 > 0.f ? v3 : 0.f;
      atomicMax(&pooled[(size_t)c*D + j*4+0], __float_as_uint(v0));
      atomicMax(&pooled[(size_t)c*D + j*4+1], __float_as_uint(v1));
      atomicMax(&pooled[(size_t)c*D + j*4+2], __float_as_uint(v2));
      atomicMax(&pooled[(size_t)c*D + j*4+3], __float_as_uint(v3));
    }
  }
}

// ---------------- readout + head ----------------

__global__ void readout_k(const float* __restrict__ hm, const int* __restrict__ batch,
                          float* __restrict__ gsum, float* __restrict__ gcnt){
  int c = blockIdx.x * blockDim.x + threadIdx.x;
  if (c >= C2N) return;
  int b = batch[c];
  atomicAdd(&gcnt[b], 1.f);
  #pragma unroll
  for (int j = 0; j < 32; ++j) atomicAdd(&gsum[(size_t)b*32 + j], hm[(size_t)c*32 + j]);
}

__global__ void head_k(const float* __restrict__ gsum, const float* __restrict__ gcnt,
                       const float* __restrict__ Wfc1, const float* __restrict__ bfc1,
                       const float* __restrict__ Wfc2, const float* __restrict__ bfc2,
                       float* __restrict__ out){
  int b = threadIdx.x;
  if (b >= BN) return;
  float cnt = gcnt[b]; if (cnt < 1.f) cnt = 1.f;
  float g[32];
  #pragma unroll
  for (int j = 0; j < 32; ++j) g[j] = gsum[(size_t)b*32 + j] / cnt;
  float acc = 0.f;
  for (int k = 0; k < 64; ++k){
    float t = bfc1[k];
    #pragma unroll
    for (int j = 0; j < 32; ++j) t += g[j] * Wfc1[j*64 + k];
    t = t > 0.f ? t : 0.f;
    acc += t * Wfc2[k];
  }
  out[b] = acc + bfc2[0];
}

// ---------------- launch ----------------

extern "C" void kernel_launch(void* const* d_in, const int* in_sizes, int n_in,
                              void* d_out, int out_size, void* d_ws, size_t ws_size,
                              hipStream_t stream) {
  const float* x        = (const float*)d_in[0];
  const int*   ei       = (const int*)  d_in[1];   // [2, E1]: src = ei, dst = ei+E1
  const float* ea       = (const float*)d_in[2];
  const int*   cluster1 = (const int*)  d_in[3];
  const int*   ei2      = (const int*)  d_in[4];   // [2, E2]
  const float* ea2      = (const float*)d_in[5];
  const int*   cluster2 = (const int*)  d_in[6];
  const int*   batch    = (const int*)  d_in[7];
  const float* W1   = (const float*)d_in[8];
  const float* att1 = (const float*)d_in[9];
  const float* b1   = (const float*)d_in[10];
  const float* W2   = (const float*)d_in[11];
  const float* att2 = (const float*)d_in[12];
  const float* b2   = (const float*)d_in[13];
  const float* Wfc1 = (const float*)d_in[14];
  const float* bfc1 = (const float*)d_in[15];
  const float* Wfc2 = (const float*)d_in[16];
  const float* bfc2 = (const float*)d_in[17];

  float* ws = (float*)d_ws;
  // ---- zero-initialized block (one small memset; all sizes multiples of 4) ----
  float* hp   = ws;                          // C1N*16 (float bits via atomicMax)
  float* hm   = hp   + (size_t)C1N*16;       // C2N*32
  float* gsum = hm   + (size_t)C2N*32;       // BN*32
  float* gcnt = gsum + (size_t)BN*32;        // BN
  int*   deg1 = (int*)(gcnt + BN);           // NN
  int*   cur1 = deg1 + NN;                   // NN
  int*   row1 = cur1 + NN;                   // NN+4  (row1[0]=0 via memset)
  int*   deg2 = row1 + NN + 4;               // C1N
  int*   cur2 = deg2 + C1N;                  // C1N
  int*   row2 = cur2 + C1N;                  // C1N+4
  char*  zend = (char*)(row2 + C1N + 4);
  size_t zbytes = (size_t)(zend - (char*)ws);
  // ---- write-before-read block ----
  float* h1    = (float*)zend;               // NN*16
  float* ad1   = h1    + (size_t)NN*16;      // NN
  float* as1   = ad1   + NN;                 // NN
  float* h2    = as1   + NN;                 // C1N*32
  float* ad2   = h2    + (size_t)C1N*32;     // C1N
  float* as2   = ad2   + C1N;                // C1N
  int*   csrc1 = (int*)(as2 + C1N);          // E1N
  float* cwv1  = (float*)(csrc1 + E1N);      // E1N
  int*   csrc2 = (int*)(cwv1 + E1N);         // E2N
  float* cwv2  = (float*)(csrc2 + E2N);      // E2N
  int*   bsum  = (int*)(cwv2 + E2N);         // 256

  hipMemsetAsync(ws, 0, zbytes, stream);

  const int nb1 = (NN  + SCAN_T*SCAN_E - 1) / (SCAN_T*SCAN_E);   // 98
  const int nb2 = (C1N + SCAN_T*SCAN_E - 1) / (SCAN_T*SCAN_E);   // 25

  // conv1: transform + CSR + aggregate/pool
  node1_k<<<(NN + 255)/256, 256, 0, stream>>>(x, W1, att1, h1, ad1, as1);
  deg_k<<<(E1N + 255)/256, 256, 0, stream>>>(ei + E1N, deg1, E1N);
  scan_block_k<<<nb1, SCAN_T, 0, stream>>>(deg1, row1 + 1, bsum, NN);
  scan_top_k<<<1, 64, 0, stream>>>(bsum, nb1);
  scan_add_k<<<nb1, SCAN_T, 0, stream>>>(row1 + 1, bsum, NN);
  scatter_k<<<(E1N + 255)/256, 256, 0, stream>>>(ei, ei + E1N, ea, row1, cur1, csrc1, cwv1, E1N);
  agg_pool_k<16,8><<<((size_t)NN*8 + 255)/256, 256, 0, stream>>>(
      row1, csrc1, cwv1, ad1, as1, h1, b1, cluster1, (unsigned*)hp, NN);

  // conv2 on pooled graph
  node2_k<<<(C1N + 255)/256, 256, 0, stream>>>(hp, W2, att2, h2, ad2, as2);
  deg_k<<<(E2N + 255)/256, 256, 0, stream>>>(ei2 + E2N, deg2, E2N);
  scan_block_k<<<nb2, SCAN_T, 0, stream>>>(deg2, row2 + 1, bsum, C1N);
  scan_top_k<<<1, 64, 0, stream>>>(bsum, nb2);
  scan_add_k<<<nb2, SCAN_T, 0, stream>>>(row2 + 1, bsum, C1N);
  scatter_k<<<(E2N + 255)/256, 256, 0, stream>>>(ei2, ei2 + E2N, ea2, row2, cur2, csrc2, cwv2, E2N);
  agg_pool_k<32,8><<<((size_t)C1N*8 + 255)/256, 256, 0, stream>>>(
      row2, csrc2, cwv2, ad2, as2, h2, b2, cluster2, (unsigned*)hm, C1N);

  // readout + head
  readout_k<<<(C2N + 255)/256, 256, 0, stream>>>(hm, batch, gsum, gcnt);
  head_k<<<1, 64, 0, stream>>>(gsum, gcnt, Wfc1, bfc1, Wfc2, bfc2, (float*)d_out);
}

// Round 3
// 602.490 us; speedup vs baseline: 7.6335x; 1.4229x over previous
//
#include <hip/hip_runtime.h>
#include <math.h>

#define NN   100000
#define E1N  3200000
#define C1N  25000
#define E2N  800000
#define C2N  6250
#define BN   64

// ---------------- node feature transforms ----------------

// h = x @ W1 (N x 3 -> N x 16); ad = h . att[:16]; as = h . att[16:]
__global__ void node1_k(const float* __restrict__ x, const float* __restrict__ W1,
                        const float* __restrict__ att1,
                        float* __restrict__ h, float* __restrict__ ad, float* __restrict__ as_){
  int n = blockIdx.x * blockDim.x + threadIdx.x;
  if (n >= NN) return;
  float x0 = x[n*3+0], x1 = x[n*3+1], x2 = x[n*3+2];
  float a = 0.f, b = 0.f;
  #pragma unroll
  for (int j = 0; j < 16; ++j){
    float v = x0*W1[j] + x1*W1[16+j] + x2*W1[32+j];
    h[(size_t)n*16 + j] = v;
    a += v * att1[j];
    b += v * att1[16+j];
  }
  ad[n] = a; as_[n] = b;
}

// h2 = hp @ W2 (C1 x 16 -> C1 x 32); ad2/as2 attention halves
__global__ void node2_k(const float* __restrict__ hp, const float* __restrict__ W2,
                        const float* __restrict__ att2,
                        float* __restrict__ h2, float* __restrict__ ad2, float* __restrict__ as2){
  int n = blockIdx.x * blockDim.x + threadIdx.x;
  if (n >= C1N) return;
  float hin[16];
  #pragma unroll
  for (int f = 0; f < 16; ++f) hin[f] = hp[(size_t)n*16 + f];
  float a = 0.f, b = 0.f;
  #pragma unroll
  for (int j = 0; j < 32; ++j){
    float v = 0.f;
    #pragma unroll
    for (int f = 0; f < 16; ++f) v += hin[f] * W2[f*32 + j];
    h2[(size_t)n*32 + j] = v;
    a += v * att2[j];
    b += v * att2[32 + j];
  }
  ad2[n] = a; as2[n] = b;
}

// ---------------- CSR build: degree+rank -> scan -> atomic-free scatter ----------------

// rank[e] = arrival order of edge e at its dst; deg[d] = in-degree.
// 4 edges per thread, vectorized dst load. E must be a multiple of 4 (3.2M / 800k are).
__global__ void degrank_k(const int* __restrict__ dst, int* __restrict__ deg,
                          int* __restrict__ rank, int E4){
  int t = blockIdx.x * blockDim.x + threadIdx.x;
  if (t >= E4) return;
  int4 d4 = ((const int4*)dst)[t];
  int4 r4;
  r4.x = atomicAdd(&deg[d4.x], 1);
  r4.y = atomicAdd(&deg[d4.y], 1);
  r4.z = atomicAdd(&deg[d4.z], 1);
  r4.w = atomicAdd(&deg[d4.w], 1);
  ((int4*)rank)[t] = r4;
}

#define SCAN_T 256
#define SCAN_E 4   // 1024 elements per block

__global__ void scan_block_k(const int* __restrict__ in, int* __restrict__ out,
                             int* __restrict__ bsum, int n){
  __shared__ int lds[SCAN_T];
  int t = threadIdx.x;
  int base = blockIdx.x * (SCAN_T*SCAN_E);
  int vals[SCAN_E];
  int acc = 0;
  #pragma unroll
  for (int k = 0; k < SCAN_E; ++k){
    int i = base + t*SCAN_E + k;
    vals[k] = (i < n) ? in[i] : 0;
    acc += vals[k];
  }
  lds[t] = acc;
  __syncthreads();
  #pragma unroll
  for (int off = 1; off < SCAN_T; off <<= 1){
    int v = (t >= off) ? lds[t-off] : 0;
    __syncthreads();
    lds[t] += v;
    __syncthreads();
  }
  int run = (t > 0) ? lds[t-1] : 0;
  #pragma unroll
  for (int k = 0; k < SCAN_E; ++k){
    int i = base + t*SCAN_E + k;
    run += vals[k];
    if (i < n) out[i] = run;
  }
  if (t == SCAN_T-1) bsum[blockIdx.x] = lds[SCAN_T-1];
}

__global__ void scan_top_k(int* __restrict__ bsum, int nb){
  if (threadIdx.x == 0){
    int run = 0;
    for (int b = 0; b < nb; ++b){ run += bsum[b]; bsum[b] = run; }
  }
}

__global__ void scan_add_k(int* __restrict__ out, const int* __restrict__ bsum, int n){
  int b = blockIdx.x;
  if (b == 0) return;
  int add = bsum[b-1];
  int i0 = b*(SCAN_T*SCAN_E) + threadIdx.x;
  #pragma unroll
  for (int k = 0; k < SCAN_E; ++k){
    int i = i0 + k*SCAN_T;
    if (i < n) out[i] += add;
  }
}

// atomic-free scatter: p = row[dst] + rank; one packed 8B store per edge.
__global__ void scatter_k(const int* __restrict__ src, const int* __restrict__ dst,
                          const int* __restrict__ rank, const float* __restrict__ w,
                          const int* __restrict__ row, int2* __restrict__ pay, int E4){
  int t = blockIdx.x * blockDim.x + threadIdx.x;
  if (t >= E4) return;
  int4 s4 = ((const int4*)src)[t];
  int4 d4 = ((const int4*)dst)[t];
  int4 r4 = ((const int4*)rank)[t];
  float4 w4 = ((const float4*)w)[t];
  int2 v;
  v.x = s4.x; v.y = __float_as_int(w4.x); pay[row[d4.x] + r4.x] = v;
  v.x = s4.y; v.y = __float_as_int(w4.y); pay[row[d4.y] + r4.y] = v;
  v.x = s4.z; v.y = __float_as_int(w4.z); pay[row[d4.z] + r4.z] = v;
  v.x = s4.w; v.y = __float_as_int(w4.w); pay[row[d4.w] + r4.w] = v;
}

// ---------------- fused per-dst softmax-aggregate + relu + cluster max-pool ----------------
// Single pass (no max subtraction: logits are O(+-10), exp is fp32-safe; softmax
// ratio is mathematically identical). GRP lanes strided over the dst's CSR range.
template<int D, int GRP>
__global__ void agg_pool_k(const int* __restrict__ row, const int2* __restrict__ pay,
                           const float* __restrict__ ad, const float* __restrict__ as_,
                           const float* __restrict__ h, const float* __restrict__ bias,
                           const int* __restrict__ cl, unsigned* __restrict__ pooled, int n){
  int gid  = (blockIdx.x * blockDim.x + threadIdx.x) / GRP;
  int lane = threadIdx.x & (GRP-1);
  if (gid >= n) return;
  int beg = row[gid], end = row[gid+1];
  float adg = ad[gid];

  float s = 0.f;
  float4 acc[D/4];
  #pragma unroll
  for (int j = 0; j < D/4; ++j) acc[j] = make_float4(0.f,0.f,0.f,0.f);

  for (int p = beg + lane; p < end; p += GRP){
    int2 pv = pay[p];
    int sv = pv.x;
    float l = adg + as_[sv];
    l = l > 0.f ? l : 0.2f*l;
    float ex = __expf(l);
    s += ex;
    float c = ex * __int_as_float(pv.y);
    const float4* hs = (const float4*)(h + (size_t)sv*D);
    #pragma unroll
    for (int j = 0; j < D/4; ++j){
      float4 hv = hs[j];
      acc[j].x += c*hv.x; acc[j].y += c*hv.y; acc[j].z += c*hv.z; acc[j].w += c*hv.w;
    }
  }
  #pragma unroll
  for (int off = GRP>>1; off; off >>= 1){
    s += __shfl_xor(s, off);
    #pragma unroll
    for (int j = 0; j < D/4; ++j){
      acc[j].x += __shfl_xor(acc[j].x, off);
      acc[j].y += __shfl_xor(acc[j].y, off);
      acc[j].z += __shfl_xor(acc[j].z, off);
      acc[j].w += __shfl_xor(acc[j].w, off);
    }
  }
  float inv = s > 0.f ? 1.f/s : 0.f;   // no-edge node: out = bias
  int c = cl[gid];
  if (lane == 0){
    #pragma unroll
    for (int j = 0; j < D/4; ++j){
      float4 a4 = acc[j];
      float v0 = a4.x*inv + bias[j*4+0]; v0 = v0 > 0.f ? v0 : 0.f;
      float v1 = a4.y*inv + bias[j*4+1]; v1 = v1 > 0.f ? v1 : 0.f;
      float v2 = a4.z*inv + bias[j*4+2]; v2 = v2 > 0.f ? v2 : 0.f;
      float v3 = a4.w*inv + bias[j*4+3]; v3 = v3 > 0.f ? v3 : 0.f;
      atomicMax(&pooled[(size_t)c*D + j*4+0], __float_as_uint(v0));
      atomicMax(&pooled[(size_t)c*D + j*4+1], __float_as_uint(v1));
      atomicMax(&pooled[(size_t)c*D + j*4+2], __float_as_uint(v2));
      atomicMax(&pooled[(size_t)c*D + j*4+3], __float_as_uint(v3));
    }
  }
}

// ---------------- readout + head ----------------

__global__ void readout_k(const float* __restrict__ hm, const int* __restrict__ batch,
                          float* __restrict__ gsum, float* __restrict__ gcnt){
  int c = blockIdx.x * blockDim.x + threadIdx.x;
  if (c >= C2N) return;
  int b = batch[c];
  atomicAdd(&gcnt[b], 1.f);
  #pragma unroll
  for (int j = 0; j < 32; ++j) atomicAdd(&gsum[(size_t)b*32 + j], hm[(size_t)c*32 + j]);
}

__global__ void head_k(const float* __restrict__ gsum, const float* __restrict__ gcnt,
                       const float* __restrict__ Wfc1, const float* __restrict__ bfc1,
                       const float* __restrict__ Wfc2, const float* __restrict__ bfc2,
                       float* __restrict__ out){
  int b = threadIdx.x;
  if (b >= BN) return;
  float cnt = gcnt[b]; if (cnt < 1.f) cnt = 1.f;
  float g[32];
  #pragma unroll
  for (int j = 0; j < 32; ++j) g[j] = gsum[(size_t)b*32 + j] / cnt;
  float acc = 0.f;
  for (int k = 0; k < 64; ++k){
    float t = bfc1[k];
    #pragma unroll
    for (int j = 0; j < 32; ++j) t += g[j] * Wfc1[j*64 + k];
    t = t > 0.f ? t : 0.f;
    acc += t * Wfc2[k];
  }
  out[b] = acc + bfc2[0];
}

// ---------------- launch ----------------

extern "C" void kernel_launch(void* const* d_in, const int* in_sizes, int n_in,
                              void* d_out, int out_size, void* d_ws, size_t ws_size,
                              hipStream_t stream) {
  const float* x        = (const float*)d_in[0];
  const int*   ei       = (const int*)  d_in[1];   // [2, E1]: src = ei, dst = ei+E1
  const float* ea       = (const float*)d_in[2];
  const int*   cluster1 = (const int*)  d_in[3];
  const int*   ei2      = (const int*)  d_in[4];   // [2, E2]
  const float* ea2      = (const float*)d_in[5];
  const int*   cluster2 = (const int*)  d_in[6];
  const int*   batch    = (const int*)  d_in[7];
  const float* W1   = (const float*)d_in[8];
  const float* att1 = (const float*)d_in[9];
  const float* b1   = (const float*)d_in[10];
  const float* W2   = (const float*)d_in[11];
  const float* att2 = (const float*)d_in[12];
  const float* b2   = (const float*)d_in[13];
  const float* Wfc1 = (const float*)d_in[14];
  const float* bfc1 = (const float*)d_in[15];
  const float* Wfc2 = (const float*)d_in[16];
  const float* bfc2 = (const float*)d_in[17];

  float* ws = (float*)d_ws;
  // ---- zero-initialized block ----
  float* hp   = ws;                          // C1N*16 (float bits via atomicMax)
  float* hm   = hp   + (size_t)C1N*16;       // C2N*32
  float* gsum = hm   + (size_t)C2N*32;       // BN*32
  float* gcnt = gsum + (size_t)BN*32;        // BN
  int*   deg1 = (int*)(gcnt + BN);           // NN
  int*   row1 = deg1 + NN;                   // NN+4  (row1[0]=0 via memset)
  int*   deg2 = row1 + NN + 4;               // C1N
  int*   row2 = deg2 + C1N;                  // C1N+4
  char*  zend = (char*)(row2 + C1N + 4);
  size_t zbytes = (size_t)(zend - (char*)ws);
  // ---- write-before-read block (8B-aligned start for int2) ----
  size_t off8 = ((zbytes + 15) & ~(size_t)15);
  int2*  pay1  = (int2*)((char*)ws + off8);  // E1N int2
  int2*  pay2  = pay1 + E1N;                 // E2N int2
  float* h1    = (float*)(pay2 + E2N);       // NN*16
  float* ad1   = h1    + (size_t)NN*16;      // NN
  float* as1   = ad1   + NN;                 // NN
  float* h2    = as1   + NN;                 // C1N*32
  float* ad2   = h2    + (size_t)C1N*32;     // C1N
  float* as2   = ad2   + C1N;                // C1N
  int*   rank1 = (int*)(as2 + C1N);          // E1N  (reused as rank2)
  int*   rank2 = rank1;                      //  alias: rank1 dead after scatter1
  int*   bsum  = rank1 + E1N;                // 256

  hipMemsetAsync(ws, 0, zbytes, stream);

  const int nb1 = (NN  + SCAN_T*SCAN_E - 1) / (SCAN_T*SCAN_E);   // 98
  const int nb2 = (C1N + SCAN_T*SCAN_E - 1) / (SCAN_T*SCAN_E);   // 25

  // conv1
  node1_k<<<(NN + 255)/256, 256, 0, stream>>>(x, W1, att1, h1, ad1, as1);
  degrank_k<<<(E1N/4 + 255)/256, 256, 0, stream>>>(ei + E1N, deg1, rank1, E1N/4);
  scan_block_k<<<nb1, SCAN_T, 0, stream>>>(deg1, row1 + 1, bsum, NN);
  scan_top_k<<<1, 64, 0, stream>>>(bsum, nb1);
  scan_add_k<<<nb1, SCAN_T, 0, stream>>>(row1 + 1, bsum, NN);
  scatter_k<<<(E1N/4 + 255)/256, 256, 0, stream>>>(ei, ei + E1N, rank1, ea, row1, pay1, E1N/4);
  agg_pool_k<16,8><<<((size_t)NN*8 + 255)/256, 256, 0, stream>>>(
      row1, pay1, ad1, as1, h1, b1, cluster1, (unsigned*)hp, NN);

  // conv2
  node2_k<<<(C1N + 255)/256, 256, 0, stream>>>(hp, W2, att2, h2, ad2, as2);
  degrank_k<<<(E2N/4 + 255)/256, 256, 0, stream>>>(ei2 + E2N, deg2, rank2, E2N/4);
  scan_block_k<<<nb2, SCAN_T, 0, stream>>>(deg2, row2 + 1, bsum, C1N);
  scan_top_k<<<1, 64, 0, stream>>>(bsum, nb2);
  scan_add_k<<<nb2, SCAN_T, 0, stream>>>(row2 + 1, bsum, C1N);
  scatter_k<<<(E2N/4 + 255)/256, 256, 0, stream>>>(ei2, ei2 + E2N, rank2, ea2, row2, pay2, E2N/4);
  agg_pool_k<32,8><<<((size_t)C1N*8 + 255)/256, 256, 0, stream>>>(
      row2, pay2, ad2, as2, h2, b2, cluster2, (unsigned*)hm, C1N);

  // readout + head
  readout_k<<<(C2N + 255)/256, 256, 0, stream>>>(hm, batch, gsum, gcnt);
  head_k<<<1, 64, 0, stream>>>(gsum, gcnt, Wfc1, bfc1, Wfc2, bfc2, (float*)d_out);
}